// Round 17
// baseline (113.602 us; speedup 1.0000x reference)
//
#include <hip/hip_runtime.h>

// GraphConvBlock, v17 = v14 (best: 106.97us) with MFMA shape swapped to
// 32x32x16_bf16 (2382 vs 2075 TF ubench, half the MFMA instruction count).
// Wave = 2m x 2p frags of 32; acc = f32x16[2][2] (64 VGPR, same as v14).
// A-frag layout: row=lane&31, k=(lane>>5)*8+j (K-doubled analog of verified
// 16x16 mapping); C/D: col=lane&31, row=(reg&3)+8*(reg>>2)+4*(lane>>5)
// (HW-verified m74/m101). Acts layout/swizzle, staging split, reduction and
// epilogue discipline (wave-uniform branches, rule #20) all carried from v14.

typedef __bf16 bf16x8 __attribute__((ext_vector_type(8)));
typedef float f32x4 __attribute__((ext_vector_type(4)));
typedef float f32x16 __attribute__((ext_vector_type(16)));

union U4 { uint4 u; bf16x8 b; };

__device__ inline unsigned pk_bf16(float lo, float hi) {
  unsigned r;
  asm volatile("v_cvt_pk_bf16_f32 %0, %1, %2" : "=v"(r) : "v"(lo), "v"(hi));
  return r;
}

__device__ inline unsigned addpk(unsigned a, unsigned b) {
  float alo = __builtin_bit_cast(float, a << 16);
  float ahi = __builtin_bit_cast(float, a & 0xFFFF0000u);
  float blo = __builtin_bit_cast(float, b << 16);
  float bhi = __builtin_bit_cast(float, b & 0xFFFF0000u);
  return pk_bf16(alo + blo, ahi + bhi);
}

__device__ inline uint4 addpk4(uint4 a, uint4 b) {
  return make_uint4(addpk(a.x, b.x), addpk(a.y, b.y), addpk(a.z, b.z), addpk(a.w, b.w));
}

#define WB_WORDS 479232

// ---------------- fused setup kernel ------------------------------------------
// repack for 32x32 A-frags: chunk c=(och*9+tap); frag f=((m*2+kh)*NKS+ks),
// NKS=CIN/32; word = f*256 + lane*4 + wq; holds pk(W(oc,2*icp), W(oc,2*icp+1))
// with oc = och*64 + m*32 + (lane&31), icp = kh*(CIN/4)+ks*8+(lane>>5)*4+wq.
__global__ __launch_bounds__(512) void setup_all(
    const float* __restrict__ x, const float* __restrict__ W0,
    const float* __restrict__ Wn, unsigned* __restrict__ B0,
    unsigned* __restrict__ B1, unsigned* __restrict__ B2,
    unsigned* __restrict__ T, unsigned* __restrict__ Wb) {
  __shared__ float xl[2 * 64 * 65];
  const int tid = threadIdx.x;
  const int bid = blockIdx.x;
  const int n = bid & 7;

#pragma unroll
  for (int it = 0; it < 4; ++it) {
    unsigned gid = (unsigned)bid * 512 + tid + it * 131072u;
    if (gid < WB_WORDS) {
      const float* src;
      int CIN, c, w;
      if (gid < 36864) {
        src = W0; CIN = 64;
        c = gid >> 11; w = gid & 2047;
      } else {
        unsigned g2 = gid - 36864;
        int s = g2 / 73728; unsigned r2 = g2 % 73728;
        src = Wn + (size_t)s * 147456; CIN = 128;
        c = r2 >> 12; w = r2 & 4095;
      }
      int och = c / 9, tap = c % 9;
      int dy = tap / 3, dx = tap % 3;
      int NKS = CIN / 32;
      int f = w >> 8;
      int m = f / (2 * NKS);
      int rem = f % (2 * NKS);
      int kh = rem / NKS, ks = rem % NKS;
      int r8 = w & 255;
      int lane = r8 >> 2, wq = r8 & 3;
      int oc = och * 64 + m * 32 + (lane & 31);
      int icp = kh * (CIN / 4) + ks * 8 + (lane >> 5) * 4 + wq;
      size_t base = (((size_t)oc * CIN + 2 * icp) * 3 + dy) * 3 + dx;
      Wb[gid] = pk_bf16(src[base], src[base + 9]);
    }
  }

  {
    unsigned gid = (unsigned)bid * 512 + tid;
    if (gid < 116480) {
      unsigned* buf; int CW; unsigned u;
      if (gid < 99840) {
        buf = gid < 33280 ? B0 : (gid < 66560 ? B1 : B2);
        u = gid % 33280; CW = 64;
      } else {
        buf = T; u = gid - 99840; CW = 32;
      }
      int per_n = 65 * CW;
      int nn = u / per_n;
      unsigned v = u % per_n;
      int pix = (v * 4) / CW, cw = (v * 4) % CW;
      int row, col;
      if (pix < 66) { row = 0; col = pix; }
      else if (pix < 132) { row = 65; col = pix - 66; }
      else if (pix < 196) { row = pix - 131; col = 0; }
      else { row = pix - 195; col = 65; }
      *(uint4*)&buf[((((size_t)nn * 66 + row) * 66 + col) * CW) + cw] =
          make_uint4(0, 0, 0, 0);
    }
  }

  {
    int hh = bid >> 3;
    int sub = tid >> 8;
    int t8 = tid & 255;
    int h = hh * 2 + sub;
#pragma unroll
    for (int k = 0; k < 16; ++k) {
      int idx = t8 + k * 256;
      int ic = idx >> 6, w = idx & 63;
      xl[(sub * 64 + w) * 65 + ic] = x[(((size_t)n * 64 + ic) * 64 + h) * 64 + w];
    }
    __syncthreads();
#pragma unroll
    for (int k = 0; k < 8; ++k) {
      int idx = t8 + k * 256;
      int w = idx >> 5, icp = idx & 31;
      unsigned v = pk_bf16(xl[(sub * 64 + w) * 65 + icp * 2],
                           xl[(sub * 64 + w) * 65 + icp * 2 + 1]);
      int wp = w + 1;
      int pos = icp ^ ((wp & 7) << 2);
      T[(((size_t)n * 66 + (h + 1)) * 66 + wp) * 32 + pos] = v;
    }
  }
}

// ---------------- unified conv stage ------------------------------------------
template <int CIN, bool DUAL, bool OUTF32>
__global__ __launch_bounds__(512, 2) void conv_stage(
    const unsigned* __restrict__ in0, const unsigned* __restrict__ in1,
    const unsigned* __restrict__ wb, const float* __restrict__ bias,
    float bmult, void* __restrict__ outp) {
  constexpr int WPP = CIN / 2;
  constexpr int CHW = 64 * WPP;
  constexpr int CH_U4 = CHW / 4;
  constexpr int NKS = CIN / 32;     // K-steps of 16 per kh-half
  constexpr int ROWW = 66 * WPP;
  constexpr int ACTW = 6 * ROWW;
  constexpr int ALDS_W = (ACTW > 16384) ? ACTW : 16384;
  constexpr int R4_U4 = 4 * ROWW / 4;
  constexpr int R2_U4 = 2 * ROWW / 4;
  constexpr int AJ4 = (R4_U4 + 511) / 512;
  constexpr int LJ = (R2_U4 + 511) / 512;

  __shared__ unsigned Alds[ALDS_W];

  const int tid = threadIdx.x;
  const int lane = tid & 63;
  const int wav = tid >> 6;
  const int wr = wav >> 1;
  const int kh = wav & 1;
  const int l31 = lane & 31, h32 = lane >> 5;
  const int bid = blockIdx.x;
  const int n = bid & 7;
  const int ochalf = (bid >> 3) & 1;
  const int h0 = (bid >> 4) * 4;

  const uint4* wg = (const uint4*)(wb + (size_t)ochalf * 9 * CHW);
  const size_t abase = ((size_t)n * 66 + h0) * ROWW;
  const uint4* g0 = (const uint4*)(in0 + abase);
  const uint4* g1 = (const uint4*)(in1 + abase);

  // ---- head: stage rows 0..3 ----
#pragma unroll
  for (int j = 0; j < AJ4; ++j) {
    int i = tid + j * 512;
    if (i < R4_U4) {
      uint4 v = g0[i];
      if (DUAL) v = addpk4(v, g1[i]);
      *(uint4*)&Alds[4 * i] = v;
    }
  }

  uint4 wcur[2][NKS], wnxt[2][NKS];
#pragma unroll
  for (int m = 0; m < 2; ++m)
#pragma unroll
    for (int ks = 0; ks < NKS; ++ks)
      wcur[m][ks] = wg[((m * 2 + kh) * NKS + ks) * 64 + lane];

  __syncthreads();  // rows 0..3 visible

  f32x16 acc[2][2];
#pragma unroll
  for (int m = 0; m < 2; ++m)
#pragma unroll
    for (int p = 0; p < 2; ++p) acc[m][p] = (f32x16)0.f;

#pragma unroll
  for (int t = 0; t < 9; ++t) {
    if (t == 3) {  // seal rows 4,5 before first read
      asm volatile("s_waitcnt lgkmcnt(0)" ::: "memory");
      __builtin_amdgcn_s_barrier();
      __builtin_amdgcn_sched_barrier(0);
    }

    if (t < 8) {
#pragma unroll
      for (int m = 0; m < 2; ++m)
#pragma unroll
        for (int ks = 0; ks < NKS; ++ks)
          wnxt[m][ks] =
              wg[(t + 1) * CH_U4 + ((m * 2 + kh) * NKS + ks) * 64 + lane];
    }

    const int dy = t / 3, dx = t % 3;
    const int arow = (wr + dy) * 66;

    __builtin_amdgcn_s_setprio(1);
#pragma unroll
    for (int ks = 0; ks < NKS; ++ks) {
      bf16x8 a0, a1;
      { U4 u; u.u = wcur[0][ks]; a0 = u.b; }
      { U4 u; u.u = wcur[1][ks]; a1 = u.b; }
      const int wb0 = kh * (WPP / 2) + ks * 8 + h32 * 4;
#pragma unroll
      for (int p = 0; p < 2; ++p) {
        int col = p * 32 + l31 + dx;
        U4 u;
        u.u = *(const uint4*)&Alds[(arow + col) * WPP + (wb0 ^ ((col & 7) << 2))];
        bf16x8 b = u.b;
        acc[0][p] = __builtin_amdgcn_mfma_f32_32x32x16_bf16(a0, b, acc[0][p], 0, 0, 0);
        acc[1][p] = __builtin_amdgcn_mfma_f32_32x32x16_bf16(a1, b, acc[1][p], 0, 0, 0);
      }
    }
    __builtin_amdgcn_s_setprio(0);

    if (t == 0) {  // commit rows 4,5 (L2-warm re-read)
#pragma unroll
      for (int j = 0; j < LJ; ++j) {
        int i = tid + j * 512;
        if (i < R2_U4) {
          uint4 v = g0[R4_U4 + i];
          if (DUAL) v = addpk4(v, g1[R4_U4 + i]);
          *(uint4*)&Alds[4 * (R4_U4 + i)] = v;
        }
      }
    }

#pragma unroll
    for (int m = 0; m < 2; ++m)
#pragma unroll
      for (int ks = 0; ks < NKS; ++ks) wcur[m][ks] = wnxt[m][ks];
  }

  // ---- symmetric half-exchange reduction (wave-uniform branches, rule #20) ----
  // kh=0 owns p0 / sends p1; kh=1 owns p1 / sends p0. Slot tag = sender kh.
  __syncthreads();
  float* R = (float*)Alds;
  if (kh) {  // send p0
#pragma unroll
    for (int m = 0; m < 2; ++m)
#pragma unroll
      for (int qt = 0; qt < 4; ++qt) {
        f32x4 tv;
        tv[0] = acc[m][0][4 * qt + 0]; tv[1] = acc[m][0][4 * qt + 1];
        tv[2] = acc[m][0][4 * qt + 2]; tv[3] = acc[m][0][4 * qt + 3];
        *(f32x4*)&R[((((wr * 2 + 1) * 2 + m) * 4) + qt) * 256 + lane * 4] = tv;
      }
  } else {   // send p1
#pragma unroll
    for (int m = 0; m < 2; ++m)
#pragma unroll
      for (int qt = 0; qt < 4; ++qt) {
        f32x4 tv;
        tv[0] = acc[m][1][4 * qt + 0]; tv[1] = acc[m][1][4 * qt + 1];
        tv[2] = acc[m][1][4 * qt + 2]; tv[3] = acc[m][1][4 * qt + 3];
        *(f32x4*)&R[((((wr * 2 + 0) * 2 + m) * 4) + qt) * 256 + lane * 4] = tv;
      }
  }
  __syncthreads();
  if (kh) {  // own p1: partner (kh=0) sent p1 in slot tag 0
#pragma unroll
    for (int m = 0; m < 2; ++m)
#pragma unroll
      for (int qt = 0; qt < 4; ++qt) {
        f32x4 o = *(const f32x4*)&R[((((wr * 2 + 0) * 2 + m) * 4) + qt) * 256 + lane * 4];
        acc[m][1][4 * qt + 0] += o[0]; acc[m][1][4 * qt + 1] += o[1];
        acc[m][1][4 * qt + 2] += o[2]; acc[m][1][4 * qt + 3] += o[3];
      }
  } else {   // own p0: partner (kh=1) sent p0 in slot tag 1
#pragma unroll
    for (int m = 0; m < 2; ++m)
#pragma unroll
      for (int qt = 0; qt < 4; ++qt) {
        f32x4 o = *(const f32x4*)&R[((((wr * 2 + 1) * 2 + m) * 4) + qt) * 256 + lane * 4];
        acc[m][0][4 * qt + 0] += o[0]; acc[m][0][4 * qt + 1] += o[1];
        acc[m][0][4 * qt + 2] += o[2]; acc[m][0][4 * qt + 3] += o[3];
      }
  }

  // ---- epilogue: wave-uniform branch, constant p index ----
  // C/D: col = lane&31 (pixel), oc_local = (reg&3) + 8*(reg>>2) + 4*h32.
  const int obase = ochalf * 64;
#define EPI_F32(P)                                                              \
  {                                                                             \
    _Pragma("unroll") for (int m = 0; m < 2; ++m) {                             \
      int ocb = obase + m * 32;                                                 \
      int w = (P) * 32 + l31;                                                   \
      _Pragma("unroll") for (int g = 0; g < 4; ++g) {                           \
        int oc4 = ocb + 8 * g + 4 * h32;                                        \
        float4 bb = *(const float4*)&bias[oc4];                                 \
        _Pragma("unroll") for (int s = 0; s < 4; ++s)                           \
            ((float*)outp)[(((size_t)n * 128 + oc4 + s) * 64 + (h0 + wr)) * 64 +\
                           w] = acc[m][(P)][4 * g + s] +                        \
                                ((const float*)&bb)[s] * bmult;                 \
      }                                                                         \
    }                                                                           \
  }
#define EPI_BF16(P)                                                             \
  {                                                                             \
    _Pragma("unroll") for (int m = 0; m < 2; ++m) {                             \
      int ocb = obase + m * 32;                                                 \
      int icpb = ocb >> 1;                                                      \
      int w = (P) * 32 + l31;                                                   \
      int wp = w + 1;                                                           \
      int xorv = (wp & 7) << 2;                                                 \
      size_t gb = (((size_t)n * 66 + (h0 + 1 + wr)) * 66 + wp) * 64;            \
      _Pragma("unroll") for (int g = 0; g < 4; ++g) {                           \
        int oc4 = ocb + 8 * g + 4 * h32;                                        \
        float4 bb = *(const float4*)&bias[oc4];                                 \
        float v0 = acc[m][(P)][4 * g + 0] + bb.x * bmult;                       \
        float v1 = acc[m][(P)][4 * g + 1] + bb.y * bmult;                       \
        float v2 = acc[m][(P)][4 * g + 2] + bb.z * bmult;                       \
        float v3 = acc[m][(P)][4 * g + 3] + bb.w * bmult;                       \
        int pos = (icpb + 4 * g + 2 * h32) ^ xorv;                              \
        *(uint2*)&((unsigned*)outp)[gb + pos] =                                 \
            make_uint2(pk_bf16(v0, v1), pk_bf16(v2, v3));                       \
      }                                                                         \
    }                                                                           \
  }
  if (OUTF32) {
    if (kh) EPI_F32(1) else EPI_F32(0)
  } else {
    if (kh) EPI_BF16(1) else EPI_BF16(0)
  }
#undef EPI_F32
#undef EPI_BF16
}

// ---------------- launch ------------------------------------------------------
extern "C" void kernel_launch(void* const* d_in, const int* in_sizes, int n_in,
                              void* d_out, int out_size, void* d_ws,
                              size_t ws_size, hipStream_t stream) {
  const float* x = (const float*)d_in[0];
  const float* W0 = (const float*)d_in[1];
  const float* b0 = (const float*)d_in[2];
  const float* Wn = (const float*)d_in[3];
  const float* bn = (const float*)d_in[4];

  const size_t ACTB = (size_t)8 * 66 * 66 * 64;
  const size_t TW = (size_t)8 * 66 * 66 * 32;
  unsigned* B0 = (unsigned*)d_ws;
  unsigned* B1 = B0 + ACTB;
  unsigned* B2 = B1 + ACTB;
  unsigned* T = B2 + ACTB;
  unsigned* Wb = T + TW;

  setup_all<<<256, 512, 0, stream>>>(x, W0, Wn, B0, B1, B2, T, Wb);

  dim3 grid(256), blk(512);
  const unsigned* Wnode = Wb + 36864;
  const size_t NW = 73728;

  conv_stage<64, false, false><<<grid, blk, 0, stream>>>(T, T, Wb, b0, 1.f, B0);
  conv_stage<128, false, false><<<grid, blk, 0, stream>>>(B0, B0, Wnode, bn + 0, 1.f, B1);
  conv_stage<128, true, false><<<grid, blk, 0, stream>>>(B0, B1, Wnode + 1 * NW, bn + 128, 2.f, B2);
  conv_stage<128, true, false><<<grid, blk, 0, stream>>>(B1, B2, Wnode + 2 * NW, bn + 256, 2.f, B0);
  conv_stage<128, true, false><<<grid, blk, 0, stream>>>(B2, B0, Wnode + 3 * NW, bn + 384, 2.f, B1);
  conv_stage<128, true, false><<<grid, blk, 0, stream>>>(B0, B1, Wnode + 4 * NW, bn + 512, 2.f, B2);
  conv_stage<128, true, true><<<grid, blk, 0, stream>>>(B1, B2, Wnode + 5 * NW, bn + 640, 2.f, d_out);

  (void)in_sizes; (void)n_in; (void)out_size; (void)ws_size;
}

// Round 18
// 106.604 us; speedup vs baseline: 1.0657x; 1.0657x over previous
//
#include <hip/hip_runtime.h>

// GraphConvBlock, v18 == v14 verbatim (best measured: 106.97us).
// Final configuration after 17 rounds:
//  - conv linearity: conv(a,W)+conv(b,W)+2b == conv(a+b,W)+2*bias (child-sum
//    fused in staging) -> 7 convs total instead of 12.
//  - acts: bf16 padded swizzled NHWC [n][66][66][C/2 words] global layout
//    (halo zeros, XOR-ic swizzle baked in -> conflict-free ds_read_b128).
//  - weights: repacked to per-fragment coalesced layout, served to REGISTERS
//    straight from global (L1 covers the 4x wave redundancy); no weight LDS,
//    no per-phase barriers (3 barriers/stage total).
//  - wave structure: 512thr = 8 waves = 4 output rows x 2 K-halves; wave tile
//    64oc x 64pix x K/2 via 16x16x32 bf16 MFMA (acc 4x4 f32x4).
//  - split staging: rows 0-3 head; rows 4-5 committed at tail of tap 0,
//    sealed by one lgkm barrier at t=3.
//  - symmetric half-exchange K-reduction + all-wave epilogue, with
//    wave-uniform branches and compile-time acc indices (rule #20).
//  - grid 256 = 2 ochalf x 8 n x 16 hq; n=bid&7 keeps images XCD-local.

typedef __bf16 bf16x8 __attribute__((ext_vector_type(8)));
typedef float f32x4 __attribute__((ext_vector_type(4)));

union U4 { uint4 u; bf16x8 b; };

__device__ inline unsigned pk_bf16(float lo, float hi) {
  unsigned r;
  asm volatile("v_cvt_pk_bf16_f32 %0, %1, %2" : "=v"(r) : "v"(lo), "v"(hi));
  return r;
}

__device__ inline unsigned addpk(unsigned a, unsigned b) {
  float alo = __builtin_bit_cast(float, a << 16);
  float ahi = __builtin_bit_cast(float, a & 0xFFFF0000u);
  float blo = __builtin_bit_cast(float, b << 16);
  float bhi = __builtin_bit_cast(float, b & 0xFFFF0000u);
  return pk_bf16(alo + blo, ahi + bhi);
}

__device__ inline uint4 addpk4(uint4 a, uint4 b) {
  return make_uint4(addpk(a.x, b.x), addpk(a.y, b.y), addpk(a.z, b.z), addpk(a.w, b.w));
}

#define WB_WORDS 479232

// ---------------- fused setup kernel ------------------------------------------
__global__ __launch_bounds__(512) void setup_all(
    const float* __restrict__ x, const float* __restrict__ W0,
    const float* __restrict__ Wn, unsigned* __restrict__ B0,
    unsigned* __restrict__ B1, unsigned* __restrict__ B2,
    unsigned* __restrict__ T, unsigned* __restrict__ Wb) {
  __shared__ float xl[2 * 64 * 65];
  const int tid = threadIdx.x;
  const int bid = blockIdx.x;
  const int n = bid & 7;

#pragma unroll
  for (int it = 0; it < 4; ++it) {
    unsigned gid = (unsigned)bid * 512 + tid + it * 131072u;
    if (gid < WB_WORDS) {
      const float* src;
      int CIN, c, w;
      if (gid < 36864) {
        src = W0; CIN = 64;
        c = gid >> 11; w = gid & 2047;
      } else {
        unsigned g2 = gid - 36864;
        int s = g2 / 73728; unsigned r2 = g2 % 73728;
        src = Wn + (size_t)s * 147456; CIN = 128;
        c = r2 >> 12; w = r2 & 4095;
      }
      int och = c / 9, tap = c % 9;
      int dy = tap / 3, dx = tap % 3;
      int f = w >> 8;
      int nkc = CIN / 32;
      int m = f / nkc, kc = f % nkc;
      int r8 = w & 255;
      int lane = r8 >> 2, wq = r8 & 3;
      int oc = och * 64 + m * 16 + (lane & 15);
      int icp = kc * 16 + (lane >> 4) * 4 + wq;
      size_t base = (((size_t)oc * CIN + 2 * icp) * 3 + dy) * 3 + dx;
      Wb[gid] = pk_bf16(src[base], src[base + 9]);
    }
  }

  {
    unsigned gid = (unsigned)bid * 512 + tid;
    if (gid < 116480) {
      unsigned* buf; int CW; unsigned u;
      if (gid < 99840) {
        buf = gid < 33280 ? B0 : (gid < 66560 ? B1 : B2);
        u = gid % 33280; CW = 64;
      } else {
        buf = T; u = gid - 99840; CW = 32;
      }
      int per_n = 65 * CW;
      int nn = u / per_n;
      unsigned v = u % per_n;
      int pix = (v * 4) / CW, cw = (v * 4) % CW;
      int row, col;
      if (pix < 66) { row = 0; col = pix; }
      else if (pix < 132) { row = 65; col = pix - 66; }
      else if (pix < 196) { row = pix - 131; col = 0; }
      else { row = pix - 195; col = 65; }
      *(uint4*)&buf[((((size_t)nn * 66 + row) * 66 + col) * CW) + cw] =
          make_uint4(0, 0, 0, 0);
    }
  }

  {
    int hh = bid >> 3;
    int sub = tid >> 8;
    int t8 = tid & 255;
    int h = hh * 2 + sub;
#pragma unroll
    for (int k = 0; k < 16; ++k) {
      int idx = t8 + k * 256;
      int ic = idx >> 6, w = idx & 63;
      xl[(sub * 64 + w) * 65 + ic] = x[(((size_t)n * 64 + ic) * 64 + h) * 64 + w];
    }
    __syncthreads();
#pragma unroll
    for (int k = 0; k < 8; ++k) {
      int idx = t8 + k * 256;
      int w = idx >> 5, icp = idx & 31;
      unsigned v = pk_bf16(xl[(sub * 64 + w) * 65 + icp * 2],
                           xl[(sub * 64 + w) * 65 + icp * 2 + 1]);
      int wp = w + 1;
      int pos = icp ^ ((wp & 7) << 2);
      T[(((size_t)n * 66 + (h + 1)) * 66 + wp) * 32 + pos] = v;
    }
  }
}

// ---------------- unified conv stage ------------------------------------------
template <int CIN, bool DUAL, bool OUTF32>
__global__ __launch_bounds__(512, 2) void conv_stage(
    const unsigned* __restrict__ in0, const unsigned* __restrict__ in1,
    const unsigned* __restrict__ wb, const float* __restrict__ bias,
    float bmult, void* __restrict__ outp) {
  constexpr int WPP = CIN / 2;
  constexpr int CHW = 64 * WPP;
  constexpr int CH_U4 = CHW / 4;
  constexpr int NKC_TOT = WPP / 16;
  constexpr int KCW = NKC_TOT / 2;
  constexpr int ROWW = 66 * WPP;
  constexpr int ACTW = 6 * ROWW;
  constexpr int ALDS_W = (ACTW > 16384) ? ACTW : 16384;
  constexpr int R4_U4 = 4 * ROWW / 4;
  constexpr int R2_U4 = 2 * ROWW / 4;
  constexpr int AJ4 = (R4_U4 + 511) / 512;
  constexpr int LJ = (R2_U4 + 511) / 512;

  __shared__ unsigned Alds[ALDS_W];

  const int tid = threadIdx.x;
  const int lane = tid & 63;
  const int wav = tid >> 6;
  const int wr = wav >> 1;
  const int kh = wav & 1;
  const int l15 = lane & 15, q = lane >> 4;
  const int bid = blockIdx.x;
  const int n = bid & 7;
  const int ochalf = (bid >> 3) & 1;
  const int h0 = (bid >> 4) * 4;

  const uint4* wg = (const uint4*)(wb + (size_t)ochalf * 9 * CHW);
  const size_t abase = ((size_t)n * 66 + h0) * ROWW;
  const uint4* g0 = (const uint4*)(in0 + abase);
  const uint4* g1 = (const uint4*)(in1 + abase);

  // ---- head: stage rows 0..3 ----
#pragma unroll
  for (int j = 0; j < AJ4; ++j) {
    int i = tid + j * 512;
    if (i < R4_U4) {
      uint4 v = g0[i];
      if (DUAL) v = addpk4(v, g1[i]);
      *(uint4*)&Alds[4 * i] = v;
    }
  }

  uint4 wcur[4][KCW], wnxt[4][KCW];
#pragma unroll
  for (int m = 0; m < 4; ++m)
#pragma unroll
    for (int kc2 = 0; kc2 < KCW; ++kc2)
      wcur[m][kc2] = wg[(m * NKC_TOT + kh * KCW + kc2) * 64 + lane];

  __syncthreads();  // rows 0..3 visible

  f32x4 acc[4][4];
#pragma unroll
  for (int m = 0; m < 4; ++m)
#pragma unroll
    for (int p = 0; p < 4; ++p) acc[m][p] = (f32x4)0.f;

#pragma unroll
  for (int t = 0; t < 9; ++t) {
    if (t == 3) {  // seal rows 4,5 before first read
      asm volatile("s_waitcnt lgkmcnt(0)" ::: "memory");
      __builtin_amdgcn_s_barrier();
      __builtin_amdgcn_sched_barrier(0);
    }

    if (t < 8) {
#pragma unroll
      for (int m = 0; m < 4; ++m)
#pragma unroll
        for (int kc2 = 0; kc2 < KCW; ++kc2)
          wnxt[m][kc2] =
              wg[(t + 1) * CH_U4 + (m * NKC_TOT + kh * KCW + kc2) * 64 + lane];
    }

    const int dy = t / 3, dx = t % 3;
    const int arow = (wr + dy) * 66;

    __builtin_amdgcn_s_setprio(1);
#pragma unroll
    for (int kc2 = 0; kc2 < KCW; ++kc2) {
      const int kc = kh * KCW + kc2;
      bf16x8 a[4];
#pragma unroll
      for (int m = 0; m < 4; ++m) {
        U4 u; u.u = wcur[m][kc2]; a[m] = u.b;
      }
#pragma unroll
      for (int p = 0; p < 4; ++p) {
        int col = p * 16 + l15 + dx;
        U4 u;
        u.u = *(const uint4*)&Alds[(arow + col) * WPP +
                                   ((kc * 16 + q * 4) ^ ((col & 7) << 2))];
        bf16x8 b = u.b;
#pragma unroll
        for (int m = 0; m < 4; ++m)
          acc[m][p] =
              __builtin_amdgcn_mfma_f32_16x16x32_bf16(a[m], b, acc[m][p], 0, 0, 0);
      }
    }
    __builtin_amdgcn_s_setprio(0);

    if (t == 0) {  // commit rows 4,5 (L2-warm re-read)
#pragma unroll
      for (int j = 0; j < LJ; ++j) {
        int i = tid + j * 512;
        if (i < R2_U4) {
          uint4 v = g0[R4_U4 + i];
          if (DUAL) v = addpk4(v, g1[R4_U4 + i]);
          *(uint4*)&Alds[4 * (R4_U4 + i)] = v;
        }
      }
    }

#pragma unroll
    for (int m = 0; m < 4; ++m)
#pragma unroll
      for (int kc2 = 0; kc2 < KCW; ++kc2) wcur[m][kc2] = wnxt[m][kc2];
  }

  // ---- symmetric half-exchange reduction (wave-uniform branches, rule #20) ----
  __syncthreads();
  float* R = (float*)Alds;
  if (kh) {  // send p0,p1
#pragma unroll
    for (int m = 0; m < 4; ++m) {
      *(f32x4*)&R[(((wr * 2 + 1) * 8) + m * 2 + 0) * 256 + lane * 4] = acc[m][0];
      *(f32x4*)&R[(((wr * 2 + 1) * 8) + m * 2 + 1) * 256 + lane * 4] = acc[m][1];
    }
  } else {   // send p2,p3
#pragma unroll
    for (int m = 0; m < 4; ++m) {
      *(f32x4*)&R[(((wr * 2 + 0) * 8) + m * 2 + 0) * 256 + lane * 4] = acc[m][2];
      *(f32x4*)&R[(((wr * 2 + 0) * 8) + m * 2 + 1) * 256 + lane * 4] = acc[m][3];
    }
  }
  __syncthreads();
  if (kh) {  // own p2,p3
#pragma unroll
    for (int m = 0; m < 4; ++m) {
      acc[m][2] += *(const f32x4*)&R[(((wr * 2 + 0) * 8) + m * 2 + 0) * 256 + lane * 4];
      acc[m][3] += *(const f32x4*)&R[(((wr * 2 + 0) * 8) + m * 2 + 1) * 256 + lane * 4];
    }
  } else {   // own p0,p1
#pragma unroll
    for (int m = 0; m < 4; ++m) {
      acc[m][0] += *(const f32x4*)&R[(((wr * 2 + 1) * 8) + m * 2 + 0) * 256 + lane * 4];
      acc[m][1] += *(const f32x4*)&R[(((wr * 2 + 1) * 8) + m * 2 + 1) * 256 + lane * 4];
    }
  }

  // ---- epilogue: wave-uniform branch, constant p indices ----
  const int obase = ochalf * 64;
#define EPI_F32(P)                                                              \
  {                                                                             \
    _Pragma("unroll") for (int m = 0; m < 4; ++m) {                             \
      int oc0 = obase + m * 16 + q * 4;                                         \
      float4 bb = *(const float4*)&bias[oc0];                                   \
      int w = (P) * 16 + l15;                                                   \
      _Pragma("unroll") for (int j = 0; j < 4; ++j)                             \
          ((float*)outp)[(((size_t)n * 128 + oc0 + j) * 64 + (h0 + wr)) * 64 +  \
                         w] = acc[m][(P)][j] + ((const float*)&bb)[j] * bmult;  \
    }                                                                           \
  }
#define EPI_BF16(P)                                                             \
  {                                                                             \
    _Pragma("unroll") for (int m = 0; m < 4; ++m) {                             \
      int oc0 = obase + m * 16 + q * 4;                                         \
      float4 bb = *(const float4*)&bias[oc0];                                   \
      int icp0 = oc0 >> 1;                                                      \
      int w = (P) * 16 + l15;                                                   \
      int wp = w + 1;                                                           \
      unsigned lo = pk_bf16(acc[m][(P)][0] + bb.x * bmult,                      \
                            acc[m][(P)][1] + bb.y * bmult);                     \
      unsigned hi = pk_bf16(acc[m][(P)][2] + bb.z * bmult,                      \
                            acc[m][(P)][3] + bb.w * bmult);                     \
      int pos = icp0 ^ ((wp & 7) << 2);                                         \
      size_t base = (((size_t)n * 66 + (h0 + 1 + wr)) * 66 + wp) * 64;          \
      *(uint2*)&((unsigned*)outp)[base + pos] = make_uint2(lo, hi);             \
    }                                                                           \
  }
  if (OUTF32) {
    if (kh) { EPI_F32(2); EPI_F32(3); }
    else    { EPI_F32(0); EPI_F32(1); }
  } else {
    if (kh) { EPI_BF16(2); EPI_BF16(3); }
    else    { EPI_BF16(0); EPI_BF16(1); }
  }
#undef EPI_F32
#undef EPI_BF16
}

// ---------------- launch ------------------------------------------------------
extern "C" void kernel_launch(void* const* d_in, const int* in_sizes, int n_in,
                              void* d_out, int out_size, void* d_ws,
                              size_t ws_size, hipStream_t stream) {
  const float* x = (const float*)d_in[0];
  const float* W0 = (const float*)d_in[1];
  const float* b0 = (const float*)d_in[2];
  const float* Wn = (const float*)d_in[3];
  const float* bn = (const float*)d_in[4];

  const size_t ACTB = (size_t)8 * 66 * 66 * 64;
  const size_t TW = (size_t)8 * 66 * 66 * 32;
  unsigned* B0 = (unsigned*)d_ws;
  unsigned* B1 = B0 + ACTB;
  unsigned* B2 = B1 + ACTB;
  unsigned* T = B2 + ACTB;
  unsigned* Wb = T + TW;

  setup_all<<<256, 512, 0, stream>>>(x, W0, Wn, B0, B1, B2, T, Wb);

  dim3 grid(256), blk(512);
  const unsigned* Wnode = Wb + 36864;
  const size_t NW = 73728;

  conv_stage<64, false, false><<<grid, blk, 0, stream>>>(T, T, Wb, b0, 1.f, B0);
  conv_stage<128, false, false><<<grid, blk, 0, stream>>>(B0, B0, Wnode, bn + 0, 1.f, B1);
  conv_stage<128, true, false><<<grid, blk, 0, stream>>>(B0, B1, Wnode + 1 * NW, bn + 128, 2.f, B2);
  conv_stage<128, true, false><<<grid, blk, 0, stream>>>(B1, B2, Wnode + 2 * NW, bn + 256, 2.f, B0);
  conv_stage<128, true, false><<<grid, blk, 0, stream>>>(B2, B0, Wnode + 3 * NW, bn + 384, 2.f, B1);
  conv_stage<128, true, false><<<grid, blk, 0, stream>>>(B0, B1, Wnode + 4 * NW, bn + 512, 2.f, B2);
  conv_stage<128, true, true><<<grid, blk, 0, stream>>>(B1, B2, Wnode + 5 * NW, bn + 640, 2.f, d_out);

  (void)in_sizes; (void)n_in; (void)out_size; (void)ws_size;
}